// Round 7
// baseline (345.888 us; speedup 1.0000x reference)
//
#include <hip/hip_runtime.h>
#include <hip/hip_bf16.h>

namespace {

constexpr int K    = 19;      // classes
constexpr int C    = 256;     // channels
constexpr int HW   = 16384;   // 128*128
constexpr int B    = 8;
constexpr int REPS = 8;       // DIAGNOSTIC: amplify accum so it tops rocprof.
                              // Output is identical (idempotent stores).

typedef float f4 __attribute__((ext_vector_type(4)));
typedef int   i4 __attribute__((ext_vector_type(4)));

// ---------------------------------------------------------------------------
// Kernel 1: grid = 8 + 2048 blocks x 256 threads, 1-D so that id%8 (the XCD
// round-robin) equals the batch index -> each XCD's L2 holds one batch's
// labels. Features loaded non-temporally (zero reuse).
//   ids 0..7    : count labels for batch id (LDS columns, no atomics)
//   ids 8..2055 : class sums for (b = (id-8)&7, c = (id-8)>>3)
// LDS acc column per thread: bank = lane%32 -> 2-way aliasing only (free).
// The whole body repeats REPS times (re-zero, re-sweep, re-store).
// ---------------------------------------------------------------------------
__global__ __launch_bounds__(256) void fsl_accum(const float* __restrict__ feat,
                                                 const int* __restrict__ labels,
                                                 float* __restrict__ psums,
                                                 float* __restrict__ pcounts) {
    __shared__ float acc[4][K][64];
    const int tid  = threadIdx.x;
    const int lane = tid & 63;
    const int w    = tid >> 6;
    const int id   = blockIdx.x;

    float* mya = &acc[w][0][lane];         // class stride = 64 floats

    for (int rep = 0; rep < REPS; ++rep) {
        for (int i = tid; i < 4 * K * 64; i += 256) ((float*)acc)[i] = 0.f;
        __syncthreads();

        if (id < 8) {
            // ---- count blocks ----
            const int b = id;
            const int* lp = labels + (size_t)b * HW;
            #pragma unroll 4
            for (int it = 0; it < HW / 1024; ++it) {
                const i4 lb = *(const i4*)(lp + it * 1024 + tid * 4);
                mya[lb.x * 64] += 1.f;
                mya[lb.y * 64] += 1.f;
                mya[lb.z * 64] += 1.f;
                mya[lb.w * 64] += 1.f;
            }
            __syncthreads();
            for (int idx = tid; idx < K * 64; idx += 256) {
                const int k = idx >> 6, l = idx & 63;
                acc[0][k][l] = acc[0][k][l] + acc[1][k][l] + acc[2][k][l] + acc[3][k][l];
            }
            __syncthreads();
            for (int k = w; k < K; k += 4) {
                float v = acc[0][k][lane];
                v += __shfl_down(v, 32);
                v += __shfl_down(v, 16);
                v += __shfl_down(v, 8);
                v += __shfl_down(v, 4);
                v += __shfl_down(v, 2);
                v += __shfl_down(v, 1);
                if (lane == 0) pcounts[b * K + k] = v;
            }
        } else {
            // ---- feature-sum blocks ----
            const int b = (id - 8) & 7;
            const int c = (id - 8) >> 3;
            const float* fp = feat + (size_t)(b * C + c) * HW;
            const int*   lp = labels + (size_t)b * HW;

            #pragma unroll 4
            for (int it = 0; it < HW / 1024; ++it) {
                const int px = it * 1024 + tid * 4;
                const f4 v  = __builtin_nontemporal_load((const f4*)(fp + px));
                const i4 lb = *(const i4*)(lp + px);
                mya[lb.x * 64] += v.x;
                mya[lb.y * 64] += v.y;
                mya[lb.z * 64] += v.z;
                mya[lb.w * 64] += v.w;
            }
            __syncthreads();

            // fold 4 waves -> acc[0][k][l]
            for (int idx = tid; idx < K * 64; idx += 256) {
                const int k = idx >> 6, l = idx & 63;
                acc[0][k][l] = acc[0][k][l] + acc[1][k][l] + acc[2][k][l] + acc[3][k][l];
            }
            __syncthreads();

            // wave w reduces classes {w, w+4, ...} across 64 lanes, plain store
            for (int k = w; k < K; k += 4) {
                float v = acc[0][k][lane];
                v += __shfl_down(v, 32);
                v += __shfl_down(v, 16);
                v += __shfl_down(v, 8);
                v += __shfl_down(v, 4);
                v += __shfl_down(v, 2);
                v += __shfl_down(v, 1);
                if (lane == 0) psums[((size_t)b * K + k) * C + c] = v;
            }
        }
        __syncthreads();   // protect next rep's LDS re-zero
    }
}

// ---------------------------------------------------------------------------
// Kernel 2: reduce batch partials -> means -> L2 normalize -> 19x19 cosine
// hinge mean. Single block, 384 threads (6 waves).
// ---------------------------------------------------------------------------
__global__ __launch_bounds__(384) void fsl_finalize(const float* __restrict__ psums,
                                                    const float* __restrict__ pcounts,
                                                    float* __restrict__ out) {
    __shared__ float mm[K][260];     // padded, float4-aligned rows
    __shared__ float rcount[K];
    __shared__ float norm2s[K];
    __shared__ float rnorm[K];
    __shared__ float wred[6];
    const int tid = threadIdx.x;

    if (tid < K) {
        float cc = 0.f;
        #pragma unroll
        for (int b = 0; b < B; ++b) cc += pcounts[b * K + tid];
        rcount[tid] = 1.0f / fmaxf(cc, 1.0f);
    }
    __syncthreads();

    if (tid < C) {
        #pragma unroll
        for (int k = 0; k < K; ++k) {
            float s = 0.f;
            #pragma unroll
            for (int b = 0; b < B; ++b) s += psums[((size_t)b * K + k) * C + tid];
            mm[k][tid] = s * rcount[k];
        }
    }
    __syncthreads();

    // norms: 16 threads per class, 16 channels each, 16-lane xor-shuffle
    if (tid < K * 16) {
        const int k = tid >> 4, sub = tid & 15;
        float s = 0.f;
        #pragma unroll
        for (int j = 0; j < 16; ++j) {
            const float v = mm[k][sub + j * 16];
            s += v * v;
        }
        s += __shfl_xor(s, 8);
        s += __shfl_xor(s, 4);
        s += __shfl_xor(s, 2);
        s += __shfl_xor(s, 1);
        if (sub == 0) norm2s[k] = s;
    }
    __syncthreads();
    if (tid < K) rnorm[tid] = 1.0f / fmaxf(sqrtf(norm2s[tid]), 1e-12f);
    __syncthreads();

    // one (i,j) pair per thread: dot over 256 channels via float4 LDS reads
    float contrib = 0.f;
    if (tid < K * K) {
        const int i = tid / K;
        const int j = tid - i * K;
        const float4* ri = (const float4*)&mm[i][0];
        const float4* rj = (const float4*)&mm[j][0];
        float dot = 0.f;
        #pragma unroll 8
        for (int q = 0; q < C / 4; ++q) {
            const float4 a = ri[q], bv = rj[q];
            dot += a.x * bv.x + a.y * bv.y + a.z * bv.z + a.w * bv.w;
        }
        const float g = dot * rnorm[i] * rnorm[j];
        // MARGIN - D = g - 0.5 off-diagonal; diagonal (D=2) contributes 0
        contrib = (i == j) ? 0.f : fmaxf(g - 0.5f, 0.f);
    }

    // block reduce 384 -> 1
    float v = contrib;
    v += __shfl_down(v, 32);
    v += __shfl_down(v, 16);
    v += __shfl_down(v, 8);
    v += __shfl_down(v, 4);
    v += __shfl_down(v, 2);
    v += __shfl_down(v, 1);
    if ((tid & 63) == 0) wred[tid >> 6] = v;
    __syncthreads();
    if (tid == 0) {
        float t = 0.f;
        #pragma unroll
        for (int q = 0; q < 6; ++q) t += wred[q];
        out[0] = 1.0f * t / (float)(K * K);   // FACTOR * mean
    }
}

}  // namespace

extern "C" void kernel_launch(void* const* d_in, const int* in_sizes, int n_in,
                              void* d_out, int out_size, void* d_ws, size_t ws_size,
                              hipStream_t stream) {
    const float* feat   = (const float*)d_in[0];
    const int*   labels = (const int*)d_in[1];
    // d_in[2] (prototypes) is unused by the reference computation.

    float* psums   = (float*)d_ws;           // B*K*C floats, every slot written
    float* pcounts = psums + B * K * C;      // B*K floats, every slot written
    float* out     = (float*)d_out;

    fsl_accum<<<8 + C * B, 256, 0, stream>>>(feat, labels, psums, pcounts);
    fsl_finalize<<<1, 384, 0, stream>>>(psums, pcounts, out);
}

// Round 8
// 205.254 us; speedup vs baseline: 1.6852x; 1.6852x over previous
//
#include <hip/hip_runtime.h>
#include <hip/hip_bf16.h>

namespace {

constexpr int K  = 19;      // classes
constexpr int C  = 256;     // channels
constexpr int HW = 16384;   // 128*128
constexpr int B  = 8;

typedef float f4 __attribute__((ext_vector_type(4)));
typedef int   i4 __attribute__((ext_vector_type(4)));

// ---------------------------------------------------------------------------
// Kernel 1: grid = 8 + 2048 blocks x 256 threads, 1-D so that id%8 (the XCD
// round-robin) equals the batch index -> each XCD's L2 holds one batch's
// labels. Measured (R7, REPS diagnostic): 22-24 us/sweep = ~6.1 TB/s for the
// 134 MB feature read -> at the data-movement roofline; VALUBusy 18%,
// bank conflicts 0. Plain loads (features are L3-resident from the
// harness restore; NT hint gave no benefit and deprioritizes those lines).
//   ids 0..7    : count labels for batch id (LDS columns, no atomics)
//   ids 8..2055 : class sums for (b = (id-8)&7, c = (id-8)>>3)
// LDS acc column per thread: bank = lane%32 -> 2-way aliasing only (free).
// ---------------------------------------------------------------------------
__global__ __launch_bounds__(256) void fsl_accum(const float* __restrict__ feat,
                                                 const int* __restrict__ labels,
                                                 float* __restrict__ psums,
                                                 float* __restrict__ pcounts) {
    __shared__ float acc[4][K][64];
    const int tid  = threadIdx.x;
    const int lane = tid & 63;
    const int w    = tid >> 6;
    const int id   = blockIdx.x;

    for (int i = tid; i < 4 * K * 64; i += 256) ((float*)acc)[i] = 0.f;
    __syncthreads();

    float* mya = &acc[w][0][lane];         // class stride = 64 floats

    if (id < 8) {
        // ---- count blocks ----
        const int b = id;
        const int* lp = labels + (size_t)b * HW;
        #pragma unroll 4
        for (int it = 0; it < HW / 1024; ++it) {
            const i4 lb = *(const i4*)(lp + it * 1024 + tid * 4);
            mya[lb.x * 64] += 1.f;
            mya[lb.y * 64] += 1.f;
            mya[lb.z * 64] += 1.f;
            mya[lb.w * 64] += 1.f;
        }
        __syncthreads();
        for (int idx = tid; idx < K * 64; idx += 256) {
            const int k = idx >> 6, l = idx & 63;
            acc[0][k][l] = acc[0][k][l] + acc[1][k][l] + acc[2][k][l] + acc[3][k][l];
        }
        __syncthreads();
        for (int k = w; k < K; k += 4) {
            float v = acc[0][k][lane];
            v += __shfl_down(v, 32);
            v += __shfl_down(v, 16);
            v += __shfl_down(v, 8);
            v += __shfl_down(v, 4);
            v += __shfl_down(v, 2);
            v += __shfl_down(v, 1);
            if (lane == 0) pcounts[b * K + k] = v;
        }
        return;
    }

    // ---- feature-sum blocks ----
    const int b = (id - 8) & 7;
    const int c = (id - 8) >> 3;
    const float* fp = feat + (size_t)(b * C + c) * HW;
    const int*   lp = labels + (size_t)b * HW;

    #pragma unroll 4
    for (int it = 0; it < HW / 1024; ++it) {
        const int px = it * 1024 + tid * 4;
        const f4 v  = *(const f4*)(fp + px);
        const i4 lb = *(const i4*)(lp + px);
        mya[lb.x * 64] += v.x;
        mya[lb.y * 64] += v.y;
        mya[lb.z * 64] += v.z;
        mya[lb.w * 64] += v.w;
    }
    __syncthreads();

    // fold 4 waves -> acc[0][k][l]
    for (int idx = tid; idx < K * 64; idx += 256) {
        const int k = idx >> 6, l = idx & 63;
        acc[0][k][l] = acc[0][k][l] + acc[1][k][l] + acc[2][k][l] + acc[3][k][l];
    }
    __syncthreads();

    // wave w reduces classes {w, w+4, ...} across 64 lanes, plain store
    for (int k = w; k < K; k += 4) {
        float v = acc[0][k][lane];
        v += __shfl_down(v, 32);
        v += __shfl_down(v, 16);
        v += __shfl_down(v, 8);
        v += __shfl_down(v, 4);
        v += __shfl_down(v, 2);
        v += __shfl_down(v, 1);
        if (lane == 0) psums[((size_t)b * K + k) * C + c] = v;
    }
}

// ---------------------------------------------------------------------------
// Kernel 2: reduce batch partials -> means -> L2 normalize -> 19x19 cosine
// hinge mean. Single block, 384 threads (6 waves).
// Mean-fill rewritten: all 384 threads, float4 loads, 1216 (k,c4) tasks
// (was: 256 threads x 152 scalar loads).
// ---------------------------------------------------------------------------
__global__ __launch_bounds__(384) void fsl_finalize(const float* __restrict__ psums,
                                                    const float* __restrict__ pcounts,
                                                    float* __restrict__ out) {
    __shared__ float mm[K][260];     // padded, float4-aligned rows (1040 B)
    __shared__ float rcount[K];
    __shared__ float norm2s[K];
    __shared__ float rnorm[K];
    __shared__ float wred[6];
    const int tid = threadIdx.x;

    if (tid < K) {
        float cc = 0.f;
        #pragma unroll
        for (int b = 0; b < B; ++b) cc += pcounts[b * K + tid];
        rcount[tid] = 1.0f / fmaxf(cc, 1.0f);
    }
    __syncthreads();

    // means: task p = (k, c4); 19*64 = 1216 tasks over 384 threads,
    // 8 coalesced float4 loads per task.
    const f4* ps4 = (const f4*)psums;
    for (int p = tid; p < K * (C / 4); p += 384) {
        const int k  = p >> 6;          // p / 64
        const int c4 = p & 63;
        f4 s = {0.f, 0.f, 0.f, 0.f};
        #pragma unroll
        for (int b = 0; b < B; ++b) s += ps4[(b * K + k) * (C / 4) + c4];
        const float rc = rcount[k];
        f4* mmrow = (f4*)&mm[k][0];
        mmrow[c4] = s * rc;
    }
    __syncthreads();

    // norms: 16 threads per class, 16 channels each, 16-lane xor-shuffle
    if (tid < K * 16) {
        const int k = tid >> 4, sub = tid & 15;
        float s = 0.f;
        #pragma unroll
        for (int j = 0; j < 16; ++j) {
            const float v = mm[k][sub + j * 16];
            s += v * v;
        }
        s += __shfl_xor(s, 8);
        s += __shfl_xor(s, 4);
        s += __shfl_xor(s, 2);
        s += __shfl_xor(s, 1);
        if (sub == 0) norm2s[k] = s;
    }
    __syncthreads();
    if (tid < K) rnorm[tid] = 1.0f / fmaxf(sqrtf(norm2s[tid]), 1e-12f);
    __syncthreads();

    // one (i,j) pair per thread: dot over 256 channels via float4 LDS reads
    float contrib = 0.f;
    if (tid < K * K) {
        const int i = tid / K;
        const int j = tid - i * K;
        const float4* ri = (const float4*)&mm[i][0];
        const float4* rj = (const float4*)&mm[j][0];
        float dot = 0.f;
        #pragma unroll 8
        for (int q = 0; q < C / 4; ++q) {
            const float4 a = ri[q], bv = rj[q];
            dot += a.x * bv.x + a.y * bv.y + a.z * bv.z + a.w * bv.w;
        }
        const float g = dot * rnorm[i] * rnorm[j];
        // MARGIN - D = g - 0.5 off-diagonal; diagonal (D=2) contributes 0
        contrib = (i == j) ? 0.f : fmaxf(g - 0.5f, 0.f);
    }

    // block reduce 384 -> 1
    float v = contrib;
    v += __shfl_down(v, 32);
    v += __shfl_down(v, 16);
    v += __shfl_down(v, 8);
    v += __shfl_down(v, 4);
    v += __shfl_down(v, 2);
    v += __shfl_down(v, 1);
    if ((tid & 63) == 0) wred[tid >> 6] = v;
    __syncthreads();
    if (tid == 0) {
        float t = 0.f;
        #pragma unroll
        for (int q = 0; q < 6; ++q) t += wred[q];
        out[0] = 1.0f * t / (float)(K * K);   // FACTOR * mean
    }
}

}  // namespace

extern "C" void kernel_launch(void* const* d_in, const int* in_sizes, int n_in,
                              void* d_out, int out_size, void* d_ws, size_t ws_size,
                              hipStream_t stream) {
    const float* feat   = (const float*)d_in[0];
    const int*   labels = (const int*)d_in[1];
    // d_in[2] (prototypes) is unused by the reference computation.

    float* psums   = (float*)d_ws;           // B*K*C floats, every slot written
    float* pcounts = psums + B * K * C;      // B*K floats, every slot written
    float* out     = (float*)d_out;

    fsl_accum<<<8 + C * B, 256, 0, stream>>>(feat, labels, psums, pcounts);
    fsl_finalize<<<1, 384, 0, stream>>>(psums, pcounts, out);
}

// Round 9
// 191.101 us; speedup vs baseline: 1.8100x; 1.0741x over previous
//
#include <hip/hip_runtime.h>
#include <hip/hip_bf16.h>

namespace {

constexpr int K  = 19;      // classes
constexpr int C  = 256;     // channels
constexpr int HW = 16384;   // 128*128
constexpr int B  = 8;

typedef float f4 __attribute__((ext_vector_type(4)));
typedef int   i4 __attribute__((ext_vector_type(4)));

// ---------------------------------------------------------------------------
// Kernel 1: grid = 8 + 2048 blocks x 256 threads, 1-D so that id%8 (the XCD
// round-robin) equals the batch index -> each XCD's L2 holds one batch's
// labels (512 KB). Features MUST be loaded non-temporally: R6(NT)=192 vs
// R8(no NT)=205 us -- without NT the 134 MB zero-reuse stream evicts the
// labels from L2 and they re-fetch from L3 (~+13 us). Measured (R7 REPS
// diagnostic): 22-24 us/sweep = ~6.1 TB/s for the feature read -> at the
// data-movement roofline; VALUBusy 18%, bank conflicts 0.
//   ids 0..7    : count labels for batch id (LDS columns, no atomics)
//   ids 8..2055 : class sums for (b = (id-8)&7, c = (id-8)>>3)
// LDS acc column per thread: bank = lane%32 -> 2-way aliasing only (free).
// ---------------------------------------------------------------------------
__global__ __launch_bounds__(256) void fsl_accum(const float* __restrict__ feat,
                                                 const int* __restrict__ labels,
                                                 float* __restrict__ psums,
                                                 float* __restrict__ pcounts) {
    __shared__ float acc[4][K][64];
    const int tid  = threadIdx.x;
    const int lane = tid & 63;
    const int w    = tid >> 6;
    const int id   = blockIdx.x;

    for (int i = tid; i < 4 * K * 64; i += 256) ((float*)acc)[i] = 0.f;
    __syncthreads();

    float* mya = &acc[w][0][lane];         // class stride = 64 floats

    if (id < 8) {
        // ---- count blocks ----
        const int b = id;
        const int* lp = labels + (size_t)b * HW;
        #pragma unroll 4
        for (int it = 0; it < HW / 1024; ++it) {
            const i4 lb = *(const i4*)(lp + it * 1024 + tid * 4);
            mya[lb.x * 64] += 1.f;
            mya[lb.y * 64] += 1.f;
            mya[lb.z * 64] += 1.f;
            mya[lb.w * 64] += 1.f;
        }
        __syncthreads();
        for (int idx = tid; idx < K * 64; idx += 256) {
            const int k = idx >> 6, l = idx & 63;
            acc[0][k][l] = acc[0][k][l] + acc[1][k][l] + acc[2][k][l] + acc[3][k][l];
        }
        __syncthreads();
        for (int k = w; k < K; k += 4) {
            float v = acc[0][k][lane];
            v += __shfl_down(v, 32);
            v += __shfl_down(v, 16);
            v += __shfl_down(v, 8);
            v += __shfl_down(v, 4);
            v += __shfl_down(v, 2);
            v += __shfl_down(v, 1);
            if (lane == 0) pcounts[b * K + k] = v;
        }
        return;
    }

    // ---- feature-sum blocks ----
    const int b = (id - 8) & 7;
    const int c = (id - 8) >> 3;
    const float* fp = feat + (size_t)(b * C + c) * HW;
    const int*   lp = labels + (size_t)b * HW;

    #pragma unroll 4
    for (int it = 0; it < HW / 1024; ++it) {
        const int px = it * 1024 + tid * 4;
        const f4 v  = __builtin_nontemporal_load((const f4*)(fp + px));
        const i4 lb = *(const i4*)(lp + px);
        mya[lb.x * 64] += v.x;
        mya[lb.y * 64] += v.y;
        mya[lb.z * 64] += v.z;
        mya[lb.w * 64] += v.w;
    }
    __syncthreads();

    // fold 4 waves -> acc[0][k][l]
    for (int idx = tid; idx < K * 64; idx += 256) {
        const int k = idx >> 6, l = idx & 63;
        acc[0][k][l] = acc[0][k][l] + acc[1][k][l] + acc[2][k][l] + acc[3][k][l];
    }
    __syncthreads();

    // wave w reduces classes {w, w+4, ...} across 64 lanes, plain store
    for (int k = w; k < K; k += 4) {
        float v = acc[0][k][lane];
        v += __shfl_down(v, 32);
        v += __shfl_down(v, 16);
        v += __shfl_down(v, 8);
        v += __shfl_down(v, 4);
        v += __shfl_down(v, 2);
        v += __shfl_down(v, 1);
        if (lane == 0) psums[((size_t)b * K + k) * C + c] = v;
    }
}

// ---------------------------------------------------------------------------
// Kernel 2: reduce batch partials -> means -> L2 normalize -> 19x19 cosine
// hinge mean. Single block, 384 threads (6 waves). Mean-fill: all 384
// threads, float4 loads, 1216 (k,c4) tasks.
// ---------------------------------------------------------------------------
__global__ __launch_bounds__(384) void fsl_finalize(const float* __restrict__ psums,
                                                    const float* __restrict__ pcounts,
                                                    float* __restrict__ out) {
    __shared__ float mm[K][260];     // padded, float4-aligned rows (1040 B)
    __shared__ float rcount[K];
    __shared__ float norm2s[K];
    __shared__ float rnorm[K];
    __shared__ float wred[6];
    const int tid = threadIdx.x;

    if (tid < K) {
        float cc = 0.f;
        #pragma unroll
        for (int b = 0; b < B; ++b) cc += pcounts[b * K + tid];
        rcount[tid] = 1.0f / fmaxf(cc, 1.0f);
    }
    __syncthreads();

    // means: task p = (k, c4); 19*64 = 1216 tasks over 384 threads,
    // 8 coalesced float4 loads per task.
    const f4* ps4 = (const f4*)psums;
    for (int p = tid; p < K * (C / 4); p += 384) {
        const int k  = p >> 6;          // p / 64
        const int c4 = p & 63;
        f4 s = {0.f, 0.f, 0.f, 0.f};
        #pragma unroll
        for (int b = 0; b < B; ++b) s += ps4[(b * K + k) * (C / 4) + c4];
        const float rc = rcount[k];
        f4* mmrow = (f4*)&mm[k][0];
        mmrow[c4] = s * rc;
    }
    __syncthreads();

    // norms: 16 threads per class, 16 channels each, 16-lane xor-shuffle
    if (tid < K * 16) {
        const int k = tid >> 4, sub = tid & 15;
        float s = 0.f;
        #pragma unroll
        for (int j = 0; j < 16; ++j) {
            const float v = mm[k][sub + j * 16];
            s += v * v;
        }
        s += __shfl_xor(s, 8);
        s += __shfl_xor(s, 4);
        s += __shfl_xor(s, 2);
        s += __shfl_xor(s, 1);
        if (sub == 0) norm2s[k] = s;
    }
    __syncthreads();
    if (tid < K) rnorm[tid] = 1.0f / fmaxf(sqrtf(norm2s[tid]), 1e-12f);
    __syncthreads();

    // one (i,j) pair per thread: dot over 256 channels via float4 LDS reads
    float contrib = 0.f;
    if (tid < K * K) {
        const int i = tid / K;
        const int j = tid - i * K;
        const float4* ri = (const float4*)&mm[i][0];
        const float4* rj = (const float4*)&mm[j][0];
        float dot = 0.f;
        #pragma unroll 8
        for (int q = 0; q < C / 4; ++q) {
            const float4 a = ri[q], bv = rj[q];
            dot += a.x * bv.x + a.y * bv.y + a.z * bv.z + a.w * bv.w;
        }
        const float g = dot * rnorm[i] * rnorm[j];
        // MARGIN - D = g - 0.5 off-diagonal; diagonal (D=2) contributes 0
        contrib = (i == j) ? 0.f : fmaxf(g - 0.5f, 0.f);
    }

    // block reduce 384 -> 1
    float v = contrib;
    v += __shfl_down(v, 32);
    v += __shfl_down(v, 16);
    v += __shfl_down(v, 8);
    v += __shfl_down(v, 4);
    v += __shfl_down(v, 2);
    v += __shfl_down(v, 1);
    if ((tid & 63) == 0) wred[tid >> 6] = v;
    __syncthreads();
    if (tid == 0) {
        float t = 0.f;
        #pragma unroll
        for (int q = 0; q < 6; ++q) t += wred[q];
        out[0] = 1.0f * t / (float)(K * K);   // FACTOR * mean
    }
}

}  // namespace

extern "C" void kernel_launch(void* const* d_in, const int* in_sizes, int n_in,
                              void* d_out, int out_size, void* d_ws, size_t ws_size,
                              hipStream_t stream) {
    const float* feat   = (const float*)d_in[0];
    const int*   labels = (const int*)d_in[1];
    // d_in[2] (prototypes) is unused by the reference computation.

    float* psums   = (float*)d_ws;           // B*K*C floats, every slot written
    float* pcounts = psums + B * K * C;      // B*K floats, every slot written
    float* out     = (float*)d_out;

    fsl_accum<<<8 + C * B, 256, 0, stream>>>(feat, labels, psums, pcounts);
    fsl_finalize<<<1, 384, 0, stream>>>(psums, pcounts, out);
}